// Round 6
// baseline (746.550 us; speedup 1.0000x reference)
//
#include <hip/hip_runtime.h>
#include <cstddef>
#include <cstdint>

#define IDIV(a, b) (((a) + (b) - 1) / (b))

typedef __attribute__((ext_vector_type(8))) short short8;
typedef __attribute__((ext_vector_type(8))) unsigned short ushort8v;
typedef __attribute__((ext_vector_type(4))) float f32x4;

__device__ inline ushort f2bf_rne(float x) {
  uint32_t u = __builtin_bit_cast(uint32_t, x);
  u += 0x7fff + ((u >> 16) & 1);
  return (ushort)(u >> 16);
}
__device__ inline float bf2f(ushort h) {
  uint32_t u = (uint32_t)h << 16;
  return __builtin_bit_cast(float, u);
}

// BN coefficients from raw sums (replaces the old k_bnfin kernel)
__device__ inline void bn_coeff(const float* __restrict__ sums, const float* __restrict__ g,
                                const float* __restrict__ bb, float invN, int H, int c,
                                float& sc, float& sh) {
  const float mean = sums[c] * invN;
  float var = sums[H + c] * invN - mean * mean;
  var = var < 0.f ? 0.f : var;
  sc = g[c] * rsqrtf(var + 1e-5f);
  sh = bb[c] - mean * sc;
}

// ---------------------------------------------------------------- utilities

__global__ void k_zero_i32(int* __restrict__ p, int n) {
  int i = blockIdx.x * blockDim.x + threadIdx.x;
  if (i < n) p[i] = 0;
}

__global__ void k_zero_f32(float* __restrict__ p, int n) {
  int i = blockIdx.x * blockDim.x + threadIdx.x;
  if (i < n) p[i] = 0.f;
}

// ---------------------------------------------------------------- CSR build

__global__ void k_count(const int* __restrict__ dst, int E, int* __restrict__ cnt) {
  int i = blockIdx.x * blockDim.x + threadIdx.x;
  if (i < E) atomicAdd(&cnt[dst[i]], 1);
}

__global__ void k_scan_partial(const int* __restrict__ cnt, int n, int* __restrict__ part) {
  __shared__ int sm[256];
  const int t = threadIdx.x;
  const int i = blockIdx.x * 256 + t;
  sm[t] = (i < n) ? cnt[i] : 0;
  __syncthreads();
  for (int off = 128; off > 0; off >>= 1) {
    if (t < off) sm[t] += sm[t + off];
    __syncthreads();
  }
  if (t == 0) part[blockIdx.x] = sm[0];
}

__global__ void k_scan_offsets(int* __restrict__ part, int nb) {
  __shared__ int sm[256];
  const int t = threadIdx.x;
  if (t < nb) sm[t] = part[t];
  __syncthreads();
  if (t == 0) {
    int run = 0;
    for (int i = 0; i < nb; ++i) { int v = sm[i]; sm[i] = run; run += v; }
  }
  __syncthreads();
  if (t < nb) part[t] = sm[t];
}

__global__ void k_scan_final(const int* __restrict__ cnt, int n, const int* __restrict__ part,
                             int* __restrict__ row_ptr) {
  __shared__ int sm[256];
  const int t = threadIdx.x;
  const int i = blockIdx.x * 256 + t;
  const int v = (i < n) ? cnt[i] : 0;
  sm[t] = v;
  __syncthreads();
  for (int off = 1; off < 256; off <<= 1) {
    int x = (t >= off) ? sm[t - off] : 0;
    __syncthreads();
    sm[t] += x;
    __syncthreads();
  }
  if (i < n) row_ptr[i] = part[blockIdx.x] + sm[t] - v;  // exclusive scan
}

__global__ void k_cursor_dis(const int* __restrict__ row_ptr, const int* __restrict__ cnt,
                             int* __restrict__ cursor, float* __restrict__ dis,
                             int* __restrict__ row_ptr_end, int n, int E) {
  int i = blockIdx.x * blockDim.x + threadIdx.x;
  if (i == 0) *row_ptr_end = E;
  if (i < n) {
    cursor[i] = row_ptr[i];
    dis[i] = rsqrtf((float)cnt[i] + 1.0f);
  }
}

__global__ void k_scatter(const int* __restrict__ src, const int* __restrict__ dst, int E,
                          int* __restrict__ cursor, int* __restrict__ col) {
  int i = blockIdx.x * blockDim.x + threadIdx.x;
  if (i < E) {
    int d = dst[i];
    int pos = atomicAdd(&cursor[d], 1);
    col[pos] = src[i];
  }
}

// ---------------------------------------------------------------- weight prep
// W[K][O] fp32 -> Wt_hi[O][K], Wt_lo[O][K] bf16 (transposed + hi/lo split)

struct WSpec { const float* W; ushort* hi; ushort* lo; int K; int O; };
struct WPack { WSpec s[9]; };

__global__ void k_wprep(WPack p) {
  const WSpec w = p.s[blockIdx.y];
  const int total = w.K * w.O;
  for (int i = blockIdx.x * 256 + threadIdx.x; i < total; i += gridDim.x * 256) {
    const int o = i / w.K;
    const int k = i - o * w.K;
    const float v = w.W[(size_t)k * w.O + o];
    const ushort h = f2bf_rne(v);
    w.hi[i] = h;
    w.lo[i] = f2bf_rne(v - bf2f(h));
  }
}

// ---------------------------------------------------------------- prep pass
// out = pack_bf16( ACT ? lrelu(X*sc + sh) : X ), BN coeffs computed inline
// from raw sums; optional lo plane (SPLIT).

template <bool INBF, bool ACT, bool SPLIT, int H>
__global__ void k_prep(const void* __restrict__ Xv, const float* __restrict__ sums,
                       const float* __restrict__ g, const float* __restrict__ bb, float invN,
                       ushort* __restrict__ out, size_t planeOff, int total) {
  const int i8 = (blockIdx.x * 256 + threadIdx.x) * 8;
  if (i8 >= total) return;
  const int c0 = i8 & (H - 1);
  float f[8];
  if (INBF) {
    const ushort8v u = *reinterpret_cast<const ushort8v*>((const ushort*)Xv + i8);
#pragma unroll
    for (int j = 0; j < 8; ++j) f[j] = bf2f(u[j]);
  } else {
    const float* X = (const float*)Xv;
    const float4 a = *reinterpret_cast<const float4*>(&X[i8]);
    const float4 b = *reinterpret_cast<const float4*>(&X[i8 + 4]);
    f[0] = a.x; f[1] = a.y; f[2] = a.z; f[3] = a.w;
    f[4] = b.x; f[5] = b.y; f[6] = b.z; f[7] = b.w;
  }
  if (ACT) {
#pragma unroll
    for (int j = 0; j < 8; ++j) {
      float sc, sh;
      bn_coeff(sums, g, bb, invN, H, c0 + j, sc, sh);
      float x = f[j] * sc + sh;
      f[j] = x > 0.f ? x : 0.01f * x;
    }
  }
  ushort8v hi;
#pragma unroll
  for (int j = 0; j < 8; ++j) hi[j] = f2bf_rne(f[j]);
  *reinterpret_cast<ushort8v*>(&out[i8]) = hi;
  if (SPLIT) {
    ushort8v lo;
#pragma unroll
    for (int j = 0; j < 8; ++j) lo[j] = f2bf_rne(f[j] - bf2f(hi[j]));
    *reinterpret_cast<ushort8v*>(&out[planeOff + i8]) = lo;
  }
}

// ---------------------------------------------------------------- MFMA GEMM (no LDS)
// C[N,O] = A[N,K](bf16) @ W[K,O] (+bias). W pre-split transposed bf16 hi+lo.
// Fragments load straight from L2; depth-1 register double-buffer prefetches
// ks+1 fragments before ks's MFMA cluster (fully unrolled -> static indices).
// STATS: fused column sum/sumsq of biased output into `sums` (atomics).

template <int K, int O, bool ASPLIT, bool STATS, bool OUTBF, bool BIAS>
__launch_bounds__(256, 2)
__global__ void k_gemm2(const ushort* __restrict__ A, const ushort* __restrict__ Whi,
                        const ushort* __restrict__ Wlo, const float* __restrict__ bias,
                        void* __restrict__ Cout, float* __restrict__ sums, int N) {
  constexpr int BN = (O >= 128) ? 128 : O;
  constexpr int KS = K / 32;
  constexpr int WC = (BN == 128) ? 2 : 1;
  constexpr int WR = 4 / WC;
  constexpr int MF = (128 / WR) / 16;
  constexpr int NF = 4;

  const int bm = blockIdx.x * 128;
  const int bo = blockIdx.y * BN;
  const int t = threadIdx.x;
  const int w = t >> 6, l = t & 63;
  const int wr = w / WC, wc = w - wr * WC;
  const int r0 = wr * (MF * 16);
  const int c0 = wc * 64;
  const int lr = l & 15;
  const int lk = (l >> 4) * 8;
  const size_t loOff = (size_t)N * K;

  f32x4 acc[MF][NF];
  const f32x4 zero4 = {0.f, 0.f, 0.f, 0.f};
#pragma unroll
  for (int mf = 0; mf < MF; ++mf)
#pragma unroll
    for (int nf = 0; nf < NF; ++nf) acc[mf][nf] = zero4;

  int arow[MF];
#pragma unroll
  for (int mf = 0; mf < MF; ++mf) {
    const int r = bm + r0 + mf * 16 + lr;
    arow[mf] = r < N ? r : N - 1;
  }

  short8 ah[2][MF], al[2][MF], bh[2][NF], bl[2][NF];

  auto ldfr = [&](int ks, int b) {
#pragma unroll
    for (int nf = 0; nf < NF; ++nf) {
      const size_t boff = (size_t)(bo + c0 + nf * 16 + lr) * K + ks * 32 + lk;
      bh[b][nf] = *reinterpret_cast<const short8*>(&Whi[boff]);
      bl[b][nf] = *reinterpret_cast<const short8*>(&Wlo[boff]);
    }
#pragma unroll
    for (int mf = 0; mf < MF; ++mf) {
      const size_t aoff = (size_t)arow[mf] * K + ks * 32 + lk;
      ah[b][mf] = *reinterpret_cast<const short8*>(&A[aoff]);
      if (ASPLIT) al[b][mf] = *reinterpret_cast<const short8*>(&A[loOff + aoff]);
    }
  };

  ldfr(0, 0);
#pragma unroll
  for (int ks = 0; ks < KS; ++ks) {
    const int cur = ks & 1;
    if (ks + 1 < KS) ldfr(ks + 1, cur ^ 1);
#pragma unroll
    for (int mf = 0; mf < MF; ++mf) {
#pragma unroll
      for (int nf = 0; nf < NF; ++nf) {
        acc[mf][nf] = __builtin_amdgcn_mfma_f32_16x16x32_bf16(ah[cur][mf], bh[cur][nf], acc[mf][nf], 0, 0, 0);
        acc[mf][nf] = __builtin_amdgcn_mfma_f32_16x16x32_bf16(ah[cur][mf], bl[cur][nf], acc[mf][nf], 0, 0, 0);
        if (ASPLIT)
          acc[mf][nf] = __builtin_amdgcn_mfma_f32_16x16x32_bf16(al[cur][mf], bh[cur][nf], acc[mf][nf], 0, 0, 0);
      }
    }
  }

  // epilogue: C[row = bm+r0+mf*16+(l>>4)*4+rg][col = bo+c0+nf*16+lr]
  float s[NF], q[NF];
#pragma unroll
  for (int nf = 0; nf < NF; ++nf) { s[nf] = 0.f; q[nf] = 0.f; }
#pragma unroll
  for (int mf = 0; mf < MF; ++mf) {
    const int gr0 = bm + r0 + mf * 16 + (l >> 4) * 4;
#pragma unroll
    for (int nf = 0; nf < NF; ++nf) {
      const int gc = bo + c0 + nf * 16 + lr;
      float bval = 0.f;
      if (BIAS) bval = bias[gc];
#pragma unroll
      for (int rg = 0; rg < 4; ++rg) {
        const int row = gr0 + rg;
        if (row < N) {
          const float v = acc[mf][nf][rg] + bval;
          if (OUTBF)
            ((ushort*)Cout)[(size_t)row * O + gc] = f2bf_rne(v);
          else
            ((float*)Cout)[(size_t)row * O + gc] = v;
          if (STATS) { s[nf] += v; q[nf] += v * v; }
        }
      }
    }
  }

  if (STATS) {
    __shared__ float sred[4][NF][16][2];
#pragma unroll
    for (int nf = 0; nf < NF; ++nf) {
      s[nf] += __shfl_xor(s[nf], 16);
      s[nf] += __shfl_xor(s[nf], 32);
      q[nf] += __shfl_xor(q[nf], 16);
      q[nf] += __shfl_xor(q[nf], 32);
    }
    if (l < 16) {
#pragma unroll
      for (int nf = 0; nf < NF; ++nf) {
        sred[w][nf][l][0] = s[nf];
        sred[w][nf][l][1] = q[nf];
      }
    }
    __syncthreads();
    if (t < BN) {
      const int wcsel = (WC == 2) ? (t >> 6) : 0;
      const int nfi = (t >> 4) & 3;
      const int lri = t & 15;
      float S = 0.f, Q = 0.f;
#pragma unroll
      for (int ww = 0; ww < WR; ++ww) {
        const int w2 = ww * WC + wcsel;
        S += sred[w2][nfi][lri][0];
        Q += sred[w2][nfi][lri][1];
      }
      atomicAdd(&sums[bo + t], S);
      atomicAdd(&sums[O + bo + t], Q);
    }
  }
}

// ---------------------------------------------------------------- bf16 column stats

template <int H>
__launch_bounds__(256)
__global__ void k_colstats_bf(const ushort* __restrict__ X, int n, float* __restrict__ sums) {
  constexpr int G = H / 8;
  constexpr int NS = 256 / G;
  const int t = threadIdx.x;
  const int cg = t % G;
  const int sub = t / G;
  const int r0 = blockIdx.x * 256;
  const int rend = (r0 + 256 < n) ? r0 + 256 : n;
  float s[8], q[8];
#pragma unroll
  for (int j = 0; j < 8; ++j) { s[j] = 0.f; q[j] = 0.f; }
  for (int r = r0 + sub; r < rend; r += NS) {
    const ushort8v u = *reinterpret_cast<const ushort8v*>(&X[(size_t)r * H + cg * 8]);
#pragma unroll
    for (int j = 0; j < 8; ++j) {
      const float f = bf2f(u[j]);
      s[j] += f;
      q[j] += f * f;
    }
  }
  __shared__ float red[256][16];
#pragma unroll
  for (int j = 0; j < 8; ++j) { red[t][j] = s[j]; red[t][8 + j] = q[j]; }
  __syncthreads();
  if (sub == 0) {
#pragma unroll
    for (int k = 1; k < NS; ++k) {
      const int u2 = cg + k * G;
#pragma unroll
      for (int j = 0; j < 8; ++j) { s[j] += red[u2][j]; q[j] += red[u2][8 + j]; }
    }
#pragma unroll
    for (int j = 0; j < 8; ++j) {
      atomicAdd(&sums[cg * 8 + j], s[j]);
      atomicAdd(&sums[H + cg * 8 + j], q[j]);
    }
  }
}

// ---------------------------------------------------------------- GCN aggregation
// out[d] = sum_{e:(s->d)} Hin[s]*dis[s]*dis[d] + Hin[d]*dis[d]^2 + bias, bf16 out.
// Full wave per node, 8-deep edge batch (R4 shape). COMBINE fuses the residual:
// out = ((xin*sc+sh) + agg) * 2^-0.5 + xin, with BN coeffs computed inline.

template <int H, bool COMBINE>
__launch_bounds__(256)
__global__ void k_agg3(const ushort* __restrict__ Hin, const int* __restrict__ row_ptr,
                       const int* __restrict__ col, const float* __restrict__ dis,
                       const float* __restrict__ bias, const float* __restrict__ xin,
                       const float* __restrict__ sums, const float* __restrict__ g,
                       const float* __restrict__ bb, float invN,
                       ushort* __restrict__ out, int n) {
  constexpr int V = H / 64;
  const int lane = threadIdx.x & 63;
  const int node = blockIdx.x * 4 + (threadIdx.x >> 6);
  if (node >= n) return;
  const int beg = row_ptr[node];
  const int end = row_ptr[node + 1];
  const float dd = dis[node];
  const int lv = lane * V;
  float acc[V];
#pragma unroll
  for (int j = 0; j < V; ++j) acc[j] = 0.f;

  for (int e = beg; e < end; e += 8) {
    int s8[8];
    float w8[8];
#pragma unroll
    for (int i = 0; i < 8; ++i) {
      const bool valid = (e + i) < end;
      s8[i] = col[valid ? e + i : end - 1];
      w8[i] = valid ? dd : 0.f;
    }
#pragma unroll
    for (int i = 0; i < 8; ++i) w8[i] *= dis[s8[i]];
    if constexpr (V == 4) {
      ushort4 u[8];
#pragma unroll
      for (int i = 0; i < 8; ++i)
        u[i] = *reinterpret_cast<const ushort4*>(&Hin[(size_t)s8[i] * H + lv]);
#pragma unroll
      for (int i = 0; i < 8; ++i) {
        acc[0] += bf2f(u[i].x) * w8[i];
        acc[1] += bf2f(u[i].y) * w8[i];
        acc[2] += bf2f(u[i].z) * w8[i];
        acc[3] += bf2f(u[i].w) * w8[i];
      }
    } else {
      ushort2 u[8];
#pragma unroll
      for (int i = 0; i < 8; ++i)
        u[i] = *reinterpret_cast<const ushort2*>(&Hin[(size_t)s8[i] * H + lv]);
#pragma unroll
      for (int i = 0; i < 8; ++i) {
        acc[0] += bf2f(u[i].x) * w8[i];
        acc[1] += bf2f(u[i].y) * w8[i];
      }
    }
  }

  const float sw = dd * dd;
  float r[V];
#pragma unroll
  for (int j = 0; j < V; ++j)
    r[j] = acc[j] + bf2f(Hin[(size_t)node * H + lv + j]) * sw + bias[lv + j];

  if (COMBINE) {
    const float cinv = 0.70710678118654752f;
#pragma unroll
    for (int j = 0; j < V; ++j) {
      const float x = xin[(size_t)node * H + lv + j];
      float sc, sh;
      bn_coeff(sums, g, bb, invN, H, lv + j, sc, sh);
      r[j] = (x * sc + sh + r[j]) * cinv + x;
    }
  }

  if constexpr (V == 4) {
    ushort4 o;
    o.x = f2bf_rne(r[0]); o.y = f2bf_rne(r[1]);
    o.z = f2bf_rne(r[2]); o.w = f2bf_rne(r[3]);
    *reinterpret_cast<ushort4*>(&out[(size_t)node * H + lv]) = o;
  } else {
    ushort2 o;
    o.x = f2bf_rne(r[0]); o.y = f2bf_rne(r[1]);
    *reinterpret_cast<ushort2*>(&out[(size_t)node * H + lv]) = o;
  }
}

// ---------------------------------------------------------------- launch

extern "C" void kernel_launch(void* const* d_in, const int* in_sizes, int n_in,
                              void* d_out, int out_size, void* d_ws, size_t ws_size,
                              hipStream_t stream) {
  const int N = in_sizes[0] / 128;
  const int E = in_sizes[1] / 2;

  const float* x_vert = (const float*)d_in[0];
  const int* src = (const int*)d_in[1];
  const int* dst = src + E;
  const float* g1_lin_W = (const float*)d_in[2];
  const float* g1_lin_b = (const float*)d_in[3];
  const float* g1_c1_W = (const float*)d_in[4];
  const float* g1_c1_b = (const float*)d_in[5];
  const float* g1_c2_W = (const float*)d_in[6];
  const float* g1_c2_b = (const float*)d_in[7];
  const float* g1_n1_g = (const float*)d_in[8];
  const float* g1_n1_b = (const float*)d_in[9];
  const float* g1_n2_g = (const float*)d_in[10];
  const float* g1_n2_b = (const float*)d_in[11];
  const float* g2_lin_W = (const float*)d_in[12];
  const float* g2_lin_b = (const float*)d_in[13];
  const float* g2_c1_W = (const float*)d_in[14];
  const float* g2_c1_b = (const float*)d_in[15];
  const float* g2_c2_W = (const float*)d_in[16];
  const float* g2_c2_b = (const float*)d_in[17];
  const float* g2_n1_g = (const float*)d_in[18];
  const float* g2_n1_b = (const float*)d_in[19];
  const float* g2_n2_g = (const float*)d_in[20];
  const float* g2_n2_b = (const float*)d_in[21];
  const float* out_W = (const float*)d_in[22];
  const float* out_b = (const float*)d_in[23];
  const float* n1_g = (const float*)d_in[24];
  const float* n1_b = (const float*)d_in[25];
  const float* l1_W = (const float*)d_in[26];
  const float* l1_b = (const float*)d_in[27];
  const float* n2_g = (const float*)d_in[28];
  const float* n2_b = (const float*)d_in[29];
  const float* l2_W = (const float*)d_in[30];
  const float* l2_b = (const float*)d_in[31];

  float* out = (float*)d_out;

  // ---- workspace carve-up
  size_t off = 0;
  auto alloc = [&](size_t bytes) -> void* {
    void* p = (char*)d_ws + off;
    off += (bytes + 255) & ~(size_t)255;
    return p;
  };
  float* B1 = (float*)alloc((size_t)N * 256 * 4);    // x_in block1 (fp32 residual src)
  float* B2 = (float*)alloc((size_t)N * 128 * 4);    // x_in block2 (fp32 residual src)
  ushort* sA = (ushort*)alloc((size_t)N * 256 * 2);  // rotating bf16 slot A
  ushort* sB = (ushort*)alloc((size_t)N * 256 * 2);  // rotating bf16 slot B
  ushort* Xb = (ushort*)alloc((size_t)N * 128 * 2);  // packed x_vert
  int* cnt = (int*)alloc((size_t)N * 4);
  int* row_ptr = (int*)alloc((size_t)(N + 1) * 4);
  int* cursor = (int*)alloc((size_t)N * 4);
  int* col = (int*)alloc((size_t)E * 4);
  int* part = (int*)alloc(1024 * 4);
  float* dis = (float*)alloc((size_t)N * 4);
  float* sums = (float*)alloc(6 * 512 * 4);

  const int wk[9] = {128, 256, 256, 256, 128, 128, 128, 128, 64};
  const int wo[9] = {256, 256, 256, 128, 128, 128, 128, 64, 64};
  const float* wsrc[9] = {g1_lin_W, g1_c1_W, g1_c2_W, g2_lin_W, g2_c1_W,
                          g2_c2_W, out_W, l1_W, l2_W};
  ushort* whi[9];
  ushort* wlo[9];
  for (int i = 0; i < 9; ++i) {
    whi[i] = (ushort*)alloc((size_t)wk[i] * wo[i] * 2);
    wlo[i] = (ushort*)alloc((size_t)wk[i] * wo[i] * 2);
  }
  (void)ws_size;
  (void)n_in;
  (void)out_size;

  const int NB = IDIV(N, 256);
  const int GM = IDIV(N, 128);
  const float invN = 1.0f / (float)N;
  float* sums0 = sums + 0 * 512;
  float* sums1 = sums + 1 * 512;
  float* sums2 = sums + 2 * 512;
  float* sums3 = sums + 3 * 512;
  float* sums4 = sums + 4 * 512;
  float* sums5 = sums + 5 * 512;

  // ---- CSR build + weight prep + input pack
  k_zero_i32<<<NB, 256, 0, stream>>>(cnt, N);
  k_zero_f32<<<IDIV(6 * 512, 256), 256, 0, stream>>>(sums, 6 * 512);
  {
    WPack p;
    for (int i = 0; i < 9; ++i) p.s[i] = WSpec{wsrc[i], whi[i], wlo[i], wk[i], wo[i]};
    k_wprep<<<dim3(64, 9), 256, 0, stream>>>(p);
  }
  k_prep<false, false, false, 128><<<IDIV(N * 128, 2048), 256, 0, stream>>>(
      x_vert, nullptr, nullptr, nullptr, 0.f, Xb, 0, N * 128);
  k_count<<<IDIV(E, 256), 256, 0, stream>>>(dst, E, cnt);
  k_scan_partial<<<NB, 256, 0, stream>>>(cnt, N, part);
  k_scan_offsets<<<1, 256, 0, stream>>>(part, NB);
  k_scan_final<<<NB, 256, 0, stream>>>(cnt, N, part, row_ptr);
  k_cursor_dis<<<NB, 256, 0, stream>>>(row_ptr, cnt, cursor, dis, row_ptr + N, N, E);
  k_scatter<<<IDIV(E, 256), 256, 0, stream>>>(src, dst, E, cursor, col);

  // ================= block 1 (in 128, hid 256) =================
  k_gemm2<128, 256, false, true, false, true>
      <<<dim3(GM, 2), 256, 0, stream>>>(Xb, whi[0], wlo[0], g1_lin_b, B1, sums0, N);
  k_prep<false, true, false, 256><<<IDIV(N * 256, 2048), 256, 0, stream>>>(
      B1, sums0, g1_n1_g, g1_n1_b, invN, sA, 0, N * 256);
  k_gemm2<256, 256, false, false, true, false>
      <<<dim3(GM, 2), 256, 0, stream>>>(sA, whi[1], wlo[1], nullptr, sB, nullptr, N);
  k_agg3<256, false><<<IDIV(N, 4), 256, 0, stream>>>(
      sB, row_ptr, col, dis, g1_c1_b, nullptr, nullptr, nullptr, nullptr, 0.f, sA, N);
  k_colstats_bf<256><<<NB, 256, 0, stream>>>(sA, N, sums1);
  k_prep<true, true, false, 256><<<IDIV(N * 256, 2048), 256, 0, stream>>>(
      sA, sums1, g1_n2_g, g1_n2_b, invN, sB, 0, N * 256);
  k_gemm2<256, 256, false, false, true, false>
      <<<dim3(GM, 2), 256, 0, stream>>>(sB, whi[2], wlo[2], nullptr, sA, nullptr, N);
  k_agg3<256, true><<<IDIV(N, 4), 256, 0, stream>>>(
      sA, row_ptr, col, dis, g1_c2_b, B1, sums0, g1_n1_g, g1_n1_b, invN, sB, N);

  // ================= block 2 (in 256, hid 128) =================
  k_gemm2<256, 128, false, true, false, true>
      <<<dim3(GM, 1), 256, 0, stream>>>(sB, whi[3], wlo[3], g2_lin_b, B2, sums2, N);
  k_prep<false, true, false, 128><<<IDIV(N * 128, 2048), 256, 0, stream>>>(
      B2, sums2, g2_n1_g, g2_n1_b, invN, sA, 0, N * 128);
  k_gemm2<128, 128, false, false, true, false>
      <<<dim3(GM, 1), 256, 0, stream>>>(sA, whi[4], wlo[4], nullptr, sB, nullptr, N);
  k_agg3<128, false><<<IDIV(N, 4), 256, 0, stream>>>(
      sB, row_ptr, col, dis, g2_c1_b, nullptr, nullptr, nullptr, nullptr, 0.f, sA, N);
  k_colstats_bf<128><<<NB, 256, 0, stream>>>(sA, N, sums3);
  k_prep<true, true, false, 128><<<IDIV(N * 128, 2048), 256, 0, stream>>>(
      sA, sums3, g2_n2_g, g2_n2_b, invN, sB, 0, N * 128);
  k_gemm2<128, 128, false, false, true, false>
      <<<dim3(GM, 1), 256, 0, stream>>>(sB, whi[5], wlo[5], nullptr, sA, nullptr, N);
  k_agg3<128, true><<<IDIV(N, 4), 256, 0, stream>>>(
      sA, row_ptr, col, dis, g2_c2_b, B2, sums2, g2_n1_g, g2_n1_b, invN, sB, N);

  // ================= head =================
  k_gemm2<128, 128, false, true, true, true>
      <<<dim3(GM, 1), 256, 0, stream>>>(sB, whi[6], wlo[6], out_b, sA, sums4, N);
  k_prep<true, true, true, 128><<<IDIV(N * 128, 2048), 256, 0, stream>>>(
      sA, sums4, n1_g, n1_b, invN, sB, (size_t)N * 128, N * 128);
  k_gemm2<128, 64, true, true, true, true>
      <<<dim3(GM, 1), 256, 0, stream>>>(sB, whi[7], wlo[7], l1_b, sA, sums5, N);
  k_prep<true, true, true, 64><<<IDIV(N * 64, 2048), 256, 0, stream>>>(
      sA, sums5, n2_g, n2_b, invN, sB, (size_t)N * 64, N * 64);
  k_gemm2<64, 64, true, false, false, true>
      <<<dim3(GM, 1), 256, 0, stream>>>(sB, whi[8], wlo[8], l2_b, out, nullptr, N);
}